// Round 1
// baseline (55.038 us; speedup 1.0000x reference)
//
#include <hip/hip_runtime.h>
#include <math.h>

#define NBLK 2048
#define NTHR 256

__global__ __launch_bounds__(NTHR) void drl_main(
    const float4* __restrict__ pred,
    const float4* __restrict__ targ,
    float* __restrict__ partial,
    int B)
{
    const int tid = blockIdx.x * blockDim.x + threadIdx.x;
    const int stride = gridDim.x * blockDim.x;
    float acc = 0.0f;
    for (int i = tid; i < B; i += stride) {
        float4 p = pred[i];
        float4 t = targ[i];
        // l2-normalize quaternions (w,x,y,z)
        float n2p = p.x*p.x + p.y*p.y + p.z*p.z + p.w*p.w;
        float ip = 1.0f / fmaxf(sqrtf(n2p), 1e-12f);
        float pw = p.x*ip, px = p.y*ip, py = p.z*ip, pz = p.w*ip;
        float n2t = t.x*t.x + t.y*t.y + t.z*t.z + t.w*t.w;
        float it = 1.0f / fmaxf(sqrtf(n2t), 1e-12f);
        float tw = t.x*it, tx = t.y*it, ty = t.z*it, tz = t.w*it;
        // rotate REF=(0,0,1): v = REF + 2w*(qv x REF) + 2*(qv x (qv x REF))
        //                       = (2(wy+xz), 2(yz-wx), 1-2(x^2+y^2))
        float pvx = 2.0f*(pw*py + px*pz);
        float pvy = 2.0f*(py*pz - pw*px);
        float pvz = 1.0f - 2.0f*(px*px + py*py);
        float tvx = 2.0f*(tw*ty + tx*tz);
        float tvy = 2.0f*(ty*tz - tw*tx);
        float tvz = 1.0f - 2.0f*(tx*tx + ty*ty);
        // l2-normalize rotated vectors
        float inp = 1.0f / fmaxf(sqrtf(pvx*pvx + pvy*pvy + pvz*pvz), 1e-12f);
        float inv = 1.0f / fmaxf(sqrtf(tvx*tvx + tvy*tvy + tvz*tvz), 1e-12f);
        float c = (pvx*tvx + pvy*tvy + pvz*tvz) * inp * inv;
        c = fminf(1.0f, fmaxf(-1.0f, c));
        float a = acosf(c);
        acc += a * a;
    }
    // wave64 butterfly-ish reduce (shfl_down)
    #pragma unroll
    for (int off = 32; off > 0; off >>= 1)
        acc += __shfl_down(acc, off, 64);
    __shared__ float smem[NTHR / 64];
    const int lane = threadIdx.x & 63;
    const int wid  = threadIdx.x >> 6;
    if (lane == 0) smem[wid] = acc;
    __syncthreads();
    if (threadIdx.x == 0) {
        float s = 0.0f;
        #pragma unroll
        for (int w = 0; w < NTHR / 64; ++w) s += smem[w];
        partial[blockIdx.x] = s;
    }
}

__global__ __launch_bounds__(NTHR) void drl_finalize(
    const float* __restrict__ partial, float* __restrict__ out, int n, float invB)
{
    float acc = 0.0f;
    for (int i = threadIdx.x; i < n; i += blockDim.x) acc += partial[i];
    #pragma unroll
    for (int off = 32; off > 0; off >>= 1)
        acc += __shfl_down(acc, off, 64);
    __shared__ float smem[NTHR / 64];
    const int lane = threadIdx.x & 63;
    const int wid  = threadIdx.x >> 6;
    if (lane == 0) smem[wid] = acc;
    __syncthreads();
    if (threadIdx.x == 0) {
        float s = 0.0f;
        #pragma unroll
        for (int w = 0; w < NTHR / 64; ++w) s += smem[w];
        out[0] = s * invB;
    }
}

extern "C" void kernel_launch(void* const* d_in, const int* in_sizes, int n_in,
                              void* d_out, int out_size, void* d_ws, size_t ws_size,
                              hipStream_t stream) {
    const float4* pred = (const float4*)d_in[0];
    const float4* targ = (const float4*)d_in[1];
    float* out = (float*)d_out;
    float* partial = (float*)d_ws;   // NBLK floats of scratch
    const int B = in_sizes[0] / 4;
    drl_main<<<NBLK, NTHR, 0, stream>>>(pred, targ, partial, B);
    drl_finalize<<<1, NTHR, 0, stream>>>(partial, out, NBLK, 1.0f / (float)B);
}